// Round 15
// baseline (251.351 us; speedup 1.0000x reference)
//
#include <hip/hip_runtime.h>
#include <math.h>

#define NN 50000
#define E0 800000
#define ET 850000
#define NBX 200  // prep x-conversion blocks (+2 W transposes, +1 lw transpose)
#define NBK 196  // CSR buckets = ceil(NN/256), 256 nodes each
#define TILE 4096
#define NTILES 208  // ceil(ET/TILE)
#define CAP 8192    // per-bucket region (packed & padded csr)

typedef unsigned int uint32;
typedef unsigned short u16;
typedef __attribute__((ext_vector_type(8))) short bf16x8;  // 8 bf16 = 4 VGPRs
typedef __attribute__((ext_vector_type(4))) float f32x4;
typedef __attribute__((ext_vector_type(2))) float f32x2;

__device__ __forceinline__ u16 f2bf(float f) {
  uint32 u = __float_as_uint(f);
  return (u16)((u + 0x7FFFu + ((u >> 16) & 1u)) >> 16);  // RNE
}
__device__ __forceinline__ float bflo(uint32 u) { return __uint_as_float(u << 16); }
__device__ __forceinline__ float bfhi(uint32 u) { return __uint_as_float(u & 0xFFFF0000u); }

// ---- fused: CSR partition (blocks 0..NTILES-1) + prep (remaining blocks) ----
// LDS manually overlaid: partition needs 23.9 KB, W-transpose 16.5 KB.
__global__ __launch_bounds__(256) void partition_prep_kernel(
    const int* __restrict__ ei, int* __restrict__ gcursor, uint32* __restrict__ packed,
    const float* __restrict__ x, const float* __restrict__ W0, const float* __restrict__ W1,
    const float* __restrict__ lw,
    u16* __restrict__ xb, u16* __restrict__ w0t, u16* __restrict__ w1t, u16* __restrict__ lwt)
{
  __shared__ __align__(16) char smem[23872];
  const int b = blockIdx.x;
  const int tid = threadIdx.x;
  if (b < NTILES) {
    int* hist = (int*)smem;                       // 784
    int* s    = (int*)(smem + 784);               // 1024
    int* scanb = (int*)(smem + 1808);             // 784
    int* gofs  = (int*)(smem + 2592);             // 784
    uint32* shuf = (uint32*)(smem + 3376);        // 16384
    unsigned char* sbkt = (unsigned char*)(smem + 19760);  // 4096
    const int t0 = b * TILE;
    for (int i = tid; i < NBK; i += 256) hist[i] = 0;
    __syncthreads();
    int myb[16]; int myr[16]; uint32 mypk[16];
#pragma unroll
    for (int i = 0; i < 16; ++i) {
      int e = t0 + i * 256 + tid;
      myb[i] = -1;
      if (e < ET) {
        int src, dst;
        if (e < E0) { src = ei[e]; dst = ei[E0 + e]; }
        else        { src = e - E0; dst = src; }
        myb[i] = dst >> 8;
        mypk[i] = ((uint32)(dst & 255) << 16) | (uint32)src;
        myr[i] = atomicAdd(&hist[myb[i]], 1);
      }
    }
    __syncthreads();
    int v = (tid < NBK) ? hist[tid] : 0;
    int val = v;
    s[tid] = val;
    __syncthreads();
#pragma unroll
    for (int off = 1; off < 256; off <<= 1) {
      int t = (tid >= off) ? s[tid - off] : 0;
      __syncthreads();
      val += t;
      s[tid] = val;
      __syncthreads();
    }
    if (tid < NBK) {
      scanb[tid] = val - v;
      gofs[tid] = (v > 0) ? atomicAdd(&gcursor[tid], v) : 0;
    }
    __syncthreads();
#pragma unroll
    for (int i = 0; i < 16; ++i) {
      if (myb[i] >= 0) {
        int slot = scanb[myb[i]] + myr[i];
        shuf[slot] = mypk[i];
        sbkt[slot] = (unsigned char)myb[i];
      }
    }
    __syncthreads();
    const int tcount = (t0 + TILE <= ET) ? TILE : (ET - t0);
    for (int i = tid; i < tcount; i += 256) {
      int bb = sbkt[i];
      packed[(size_t)bb * CAP + gofs[bb] + (i - scanb[bb])] = shuf[i];
    }
  } else {
    const int b2 = b - NTILES;
    if (b2 < NBX) {
      const float4* x4 = (const float4*)x;
      ushort4* xb4 = (ushort4*)xb;
      const int total = NN * 128 / 4;
      for (int i = b2 * 256 + tid; i < total; i += NBX * 256) {
        float4 v = x4[i];
        ushort4 u;
        u.x = f2bf(v.x); u.y = f2bf(v.y); u.z = f2bf(v.z); u.w = f2bf(v.w);
        xb4[i] = u;
      }
    } else if (b2 < NBX + 2) {
      const float* W = (b2 == NBX) ? W0 : W1;
      u16* Wt = (b2 == NBX) ? w0t : w1t;
      float (*tile)[129] = (float(*)[129])smem;   // 16.5 KB overlay
      for (int k0 = 0; k0 < 128; k0 += 32) {
        __syncthreads();
#pragma unroll
        for (int it = 0; it < 4; ++it) {
          int q = tid + it * 256;
          int kk = q >> 5, n4 = (q & 31) * 4;
          float4 v = *(const float4*)&W[(k0 + kk) * 128 + n4];
          tile[kk][n4 + 0] = v.x; tile[kk][n4 + 1] = v.y;
          tile[kk][n4 + 2] = v.z; tile[kk][n4 + 3] = v.w;
        }
        __syncthreads();
        int n = tid >> 1, h = (tid & 1) * 16;
        __align__(16) u16 tmp[16];
#pragma unroll
        for (int j = 0; j < 16; ++j) tmp[j] = f2bf(tile[h + j][n]);
        *(uint4*)&Wt[n * 128 + k0 + h] = *(uint4*)&tmp[0];
        *(uint4*)&Wt[n * 128 + k0 + h + 8] = *(uint4*)&tmp[8];
      }
    } else {
      for (int idx = tid; idx < 48 * 256; idx += 256) {
        int j = idx >> 8, k = idx & 255;
        lwt[idx] = (j < 40) ? f2bf(lw[k * 40 + j]) : (u16)0;
      }
    }
  }
}

// Pass 2: per bucket, padded local CSR in LDS (sentinel = NN), coalesced writes.
__global__ __launch_bounds__(256) void build_kernel(
    const uint32* __restrict__ packed, const int* __restrict__ gcursor,
    int2* __restrict__ rowinfo, int* __restrict__ csr_src)
{
  __shared__ int h[256];
  __shared__ int s[256];
  __shared__ int sc[256];
  __shared__ int cur[256];
  __shared__ int ptot_s;
  __shared__ u16 simg[CAP];
  const int b = blockIdx.x;
  const int tid = threadIdx.x;
  const int cnt = gcursor[b];
  const uint32* pk = packed + (size_t)b * CAP;
  h[tid] = 0;
  cur[tid] = 0;
  __syncthreads();
  for (int i = tid; i < cnt; i += 256) atomicAdd(&h[(pk[i] >> 16) & 255], 1);
  __syncthreads();
  const int pd = (h[tid] + 7) & ~7;   // pad to multiple of 8
  int val = pd;
  s[tid] = val;
  __syncthreads();
#pragma unroll
  for (int off = 1; off < 256; off <<= 1) {
    int t = (tid >= off) ? s[tid - off] : 0;
    __syncthreads();
    val += t;
    s[tid] = val;
    __syncthreads();
  }
  sc[tid] = val - pd;
  if (tid == 255) ptot_s = val;
  __syncthreads();
  const int ptot = ptot_s;
  for (int i = tid; i < ptot; i += 256) simg[i] = (u16)NN;   // sentinel fill
  __syncthreads();
  for (int i = tid; i < cnt; i += 256) {
    uint32 p = pk[i];
    int dl = (p >> 16) & 255;
    int r = atomicAdd(&cur[dl], 1);
    simg[sc[dl] + r] = (u16)(p & 0xFFFFu);
  }
  __syncthreads();
  int n = b * 256 + tid;
  if (n < NN) rowinfo[n] = make_int2(b * CAP + sc[tid], pd);
  for (int i = tid; i < ptot; i += 256) csr_src[b * CAP + i] = (int)simg[i];
}

// ---------------- MFMA GEMM (Xb @ W) + attention logits ----------------
// v3: both A and B fragments direct from global (L1/L2-resident); LDS only for
// the coalesced bf16 output roundtrip + es/ed partials.
__global__ __launch_bounds__(256) void gemm_att_kernel(
    const u16* __restrict__ Xb, const u16* __restrict__ Wt,
    const float* __restrict__ avs, const float* __restrict__ avd,
    u16* __restrict__ hfeat, float* __restrict__ es, float* __restrict__ ed,
    int nnodes)
{
  __shared__ u16 hout[64 * 136];   // 17.4 KB
  __shared__ float es_s[2][64];
  __shared__ float ed_s[2][64];
  const int tid = threadIdx.x;
  const int wid = tid >> 6, lane = tid & 63;
  const int quad = lane >> 4, lc = lane & 15;
  const int n0 = blockIdx.x * 64;
  if (blockIdx.x == 0 && tid < 2) es[2 * NN + tid] = -1e30f;  // sentinel logits -> w=0

  const int arow = wid * 16 + lc;
  const int rrow = min(n0 + arow, nnodes - 1);  // clamp tail (output guarded)

  f32x4 acc[8];
#pragma unroll
  for (int t = 0; t < 8; ++t) acc[t] = (f32x4){0.f, 0.f, 0.f, 0.f};
#pragma unroll
  for (int ks = 0; ks < 4; ++ks) {
    const int k0 = ks * 32 + quad * 8;
    bf16x8 a = *(const bf16x8*)&Xb[(size_t)rrow * 128 + k0];
#pragma unroll
    for (int t = 0; t < 8; ++t) {
      bf16x8 b = *(const bf16x8*)&Wt[(t * 16 + lc) * 128 + k0];  // L2-resident
      acc[t] = __builtin_amdgcn_mfma_f32_16x16x32_bf16(a, b, acc[t], 0, 0, 0);
    }
  }

  // attention partials: quad-local shuffle reduction (single writer, no atomics)
  float av_s[8], av_d[8];
#pragma unroll
  for (int t = 0; t < 8; ++t) { av_s[t] = avs[t * 16 + lc]; av_d[t] = avd[t * 16 + lc]; }
#pragma unroll
  for (int r = 0; r < 4; ++r) {
    float s0 = 0.f, s1 = 0.f, d0 = 0.f, d1 = 0.f;
#pragma unroll
    for (int t = 0; t < 4; ++t) { s0 += acc[t][r] * av_s[t]; d0 += acc[t][r] * av_d[t]; }
#pragma unroll
    for (int t = 4; t < 8; ++t) { s1 += acc[t][r] * av_s[t]; d1 += acc[t][r] * av_d[t]; }
#pragma unroll
    for (int m = 1; m < 16; m <<= 1) {
      s0 += __shfl_xor(s0, m); s1 += __shfl_xor(s1, m);
      d0 += __shfl_xor(d0, m); d1 += __shfl_xor(d1, m);
    }
    if (lc == 0) {
      int row = wid * 16 + quad * 4 + r;
      es_s[0][row] = s0; es_s[1][row] = s1;
      ed_s[0][row] = d0; ed_s[1][row] = d1;
    }
  }
  // bf16 output roundtrip for coalesced writeback
#pragma unroll
  for (int t = 0; t < 8; ++t)
#pragma unroll
    for (int r = 0; r < 4; ++r)
      hout[(wid * 16 + quad * 4 + r) * 136 + t * 16 + lc] = f2bf(acc[t][r]);
  __syncthreads();
#pragma unroll
  for (int it = 0; it < 4; ++it) {
    int g = tid + it * 256;
    int r = g >> 4, c8 = (g & 15) * 8;
    if (n0 + r < nnodes)
      *(uint4*)&hfeat[(size_t)(n0 + r) * 128 + c8] = *(const uint4*)&hout[r * 136 + c8];
  }
  if (tid < 64) {
    int n = n0 + tid;
    if (n < nnodes) {
      es[n * 2 + 0] = es_s[0][tid]; es[n * 2 + 1] = es_s[1][tid];
      ed[n * 2 + 0] = ed_s[0][tid]; ed[n * 2 + 1] = ed_s[1][tid];
    }
  }
}

// ---------------- aggregation: one wave per node, 8 edges/iter, packed fp32 FMA ----------------
__global__ __launch_bounds__(256) void aggregate_kernel(
    const uint4* __restrict__ hfeat4, const float* __restrict__ es, const float* __restrict__ ed,
    const int2* __restrict__ rowinfo, const int* __restrict__ csr_src,
    const float* __restrict__ bias, u16* __restrict__ out, int nnodes)
{
  int n = (blockIdx.x * blockDim.x + threadIdx.x) >> 6;
  int lane = threadIdx.x & 63;
  if (n >= nnodes) return;
  const int eg = lane >> 4;
  const int fl = lane & 15;
  const int hd = (fl >= 8) ? 1 : 0;
  const int2 ri = rowinfo[n];
  const int nch = ri.y >> 3;
  const int j0 = ri.x + eg;
  const float edn = ed[n * 2 + hd];

  f32x2 acc2[4];
#pragma unroll
  for (int t = 0; t < 4; ++t) acc2[t] = (f32x2){0.f, 0.f};
  float den = 0.f;

  int i0A = csr_src[j0], i1A = csr_src[j0 + 4];
  float e0 = es[i0A * 2 + hd] + edn; e0 = fmaxf(e0, 0.2f * e0);
  float e1 = es[i1A * 2 + hd] + edn; e1 = fmaxf(e1, 0.2f * e1);
  float w0A = __expf(e0), w1A = __expf(e1);
  for (int c = 0;;) {
    uint4 h0 = hfeat4[(size_t)i0A * 16 + fl];
    uint4 h1 = hfeat4[(size_t)i1A * 16 + fl];
    bool more = (c + 1 < nch);
    int i0B, i1B; float w0B, w1B;
    if (more) {
      int jb = j0 + (c + 1) * 8;
      i0B = csr_src[jb]; i1B = csr_src[jb + 4];
      float f0 = es[i0B * 2 + hd] + edn; f0 = fmaxf(f0, 0.2f * f0);
      float f1 = es[i1B * 2 + hd] + edn; f1 = fmaxf(f1, 0.2f * f1);
      w0B = __expf(f0); w1B = __expf(f1);
    }
    f32x2 w2a = (f32x2){w0A, w0A};
    f32x2 w2b = (f32x2){w1A, w1A};
    f32x2 p;
    p = (f32x2){bflo(h0.x), bfhi(h0.x)}; acc2[0] = w2a * p + acc2[0];
    p = (f32x2){bflo(h0.y), bfhi(h0.y)}; acc2[1] = w2a * p + acc2[1];
    p = (f32x2){bflo(h0.z), bfhi(h0.z)}; acc2[2] = w2a * p + acc2[2];
    p = (f32x2){bflo(h0.w), bfhi(h0.w)}; acc2[3] = w2a * p + acc2[3];
    p = (f32x2){bflo(h1.x), bfhi(h1.x)}; acc2[0] = w2b * p + acc2[0];
    p = (f32x2){bflo(h1.y), bfhi(h1.y)}; acc2[1] = w2b * p + acc2[1];
    p = (f32x2){bflo(h1.z), bfhi(h1.z)}; acc2[2] = w2b * p + acc2[2];
    p = (f32x2){bflo(h1.w), bfhi(h1.w)}; acc2[3] = w2b * p + acc2[3];
    den += w0A + w1A;
    if (!more) break;
    i0A = i0B; i1A = i1B; w0A = w0B; w1A = w1B;
    ++c;
  }

  float acc[8] = {acc2[0].x, acc2[0].y, acc2[1].x, acc2[1].y,
                  acc2[2].x, acc2[2].y, acc2[3].x, acc2[3].y};
#pragma unroll
  for (int t = 0; t < 8; ++t) {
    acc[t] += __shfl_xor(acc[t], 16);
    acc[t] += __shfl_xor(acc[t], 32);
  }
  den += __shfl_xor(den, 16);
  den += __shfl_xor(den, 32);

  if (eg == 0) {
    float inv = 1.f / den;
    float4 b0 = *(const float4*)&bias[fl * 8];
    float4 b1 = *(const float4*)&bias[fl * 8 + 4];
    float bv[8] = {b0.x, b0.y, b0.z, b0.w, b1.x, b1.y, b1.z, b1.w};
    u16 pk[8];
#pragma unroll
    for (int t = 0; t < 8; ++t) {
      float v = acc[t] * inv + bv[t];
      v = (v > 0.f) ? v : (__expf(v) - 1.f);  // ELU
      pk[t] = f2bf(v);
    }
    uint4 o;
    o.x = (uint32)pk[0] | ((uint32)pk[1] << 16);
    o.y = (uint32)pk[2] | ((uint32)pk[3] << 16);
    o.z = (uint32)pk[4] | ((uint32)pk[5] << 16);
    o.w = (uint32)pk[6] | ((uint32)pk[7] << 16);
    ((uint4*)out)[(size_t)n * 16 + fl] = o;
  }
}

// ---------------- final: MFMA [64x256] @ [256x48] + log_softmax, zero LDS ----------------
__global__ __launch_bounds__(256) void final_kernel(
    const u16* __restrict__ h1b, const u16* __restrict__ h2b,
    const u16* __restrict__ lwt, const float* __restrict__ lb,
    float* __restrict__ out, int nnodes)
{
  const int tid = threadIdx.x;
  const int wid = tid >> 6, lane = tid & 63;
  const int quad = lane >> 4, lc = lane & 15;
  const int n0 = blockIdx.x * 64;
  const int arow = wid * 16 + lc;
  const int rrow = min(n0 + arow, nnodes - 1);

  f32x4 acc[3];
#pragma unroll
  for (int t = 0; t < 3; ++t) acc[t] = (f32x4){0.f, 0.f, 0.f, 0.f};
#pragma unroll
  for (int ks = 0; ks < 8; ++ks) {
    const u16* hsrc = (ks < 4) ? h1b : h2b;
    const int k0 = (ks & 3) * 32 + quad * 8;
    const int kl = ks * 32 + quad * 8;
    bf16x8 a = *(const bf16x8*)&hsrc[(size_t)rrow * 128 + k0];
#pragma unroll
    for (int t = 0; t < 3; ++t) {
      bf16x8 b = *(const bf16x8*)&lwt[(t * 16 + lc) * 256 + kl];  // L2-resident
      acc[t] = __builtin_amdgcn_mfma_f32_16x16x32_bf16(a, b, acc[t], 0, 0, 0);
    }
  }

  float bv[3];
  bool valid[3];
#pragma unroll
  for (int t = 0; t < 3; ++t) {
    int col = t * 16 + lc;
    valid[t] = (col < 40);
    bv[t] = valid[t] ? lb[col] : 0.f;
  }
#pragma unroll
  for (int r = 0; r < 4; ++r) {
    int row = wid * 16 + quad * 4 + r;
    int n = n0 + row;
    float v[3];
    float mx = -INFINITY;
#pragma unroll
    for (int t = 0; t < 3; ++t) {
      v[t] = acc[t][r] + bv[t];
      if (valid[t]) mx = fmaxf(mx, v[t]);
    }
    mx = fmaxf(mx, __shfl_xor(mx, 1));
    mx = fmaxf(mx, __shfl_xor(mx, 2));
    mx = fmaxf(mx, __shfl_xor(mx, 4));
    mx = fmaxf(mx, __shfl_xor(mx, 8));
    float s = 0.f;
#pragma unroll
    for (int t = 0; t < 3; ++t) if (valid[t]) s += __expf(v[t] - mx);
    s += __shfl_xor(s, 1);
    s += __shfl_xor(s, 2);
    s += __shfl_xor(s, 4);
    s += __shfl_xor(s, 8);
    float lg = mx + __logf(s);
    if (n < nnodes) {
#pragma unroll
      for (int t = 0; t < 3; ++t)
        if (valid[t]) out[(size_t)n * 40 + t * 16 + lc] = v[t] - lg;
    }
  }
}

// ---------------- launch ----------------

extern "C" void kernel_launch(void* const* d_in, const int* in_sizes, int n_in,
                              void* d_out, int out_size, void* d_ws, size_t ws_size,
                              hipStream_t stream) {
  const float* x   = (const float*)d_in[0];
  const int*   ei  = (const int*)d_in[1];
  const float* W0  = (const float*)d_in[2];
  const float* as0 = (const float*)d_in[3];
  const float* ad0 = (const float*)d_in[4];
  const float* b0  = (const float*)d_in[5];
  const float* W1  = (const float*)d_in[6];
  const float* as1 = (const float*)d_in[7];
  const float* ad1 = (const float*)d_in[8];
  const float* b1  = (const float*)d_in[9];
  const float* lw  = (const float*)d_in[10];
  const float* lb  = (const float*)d_in[11];
  float* out = (float*)d_out;

  char* p = (char*)d_ws;
  auto carve = [&](size_t bytes) { char* r = p; p += (bytes + 255) & ~(size_t)255; return r; };
  u16* xb     = (u16*)carve((size_t)NN * 128 * 2);
  u16* w0t    = (u16*)carve(128 * 128 * 2);
  u16* w1t    = (u16*)carve(128 * 128 * 2);
  u16* lwt    = (u16*)carve(48 * 256 * 2);
  u16* hfeat  = (u16*)carve((size_t)(NN + 1) * 128 * 2);  // +1 sentinel row
  u16* h1b    = (u16*)carve((size_t)NN * 128 * 2);
  u16* h2b    = (u16*)carve((size_t)NN * 128 * 2);
  float* es   = (float*)carve((size_t)(NN + 1) * 2 * 4);  // +sentinel logits
  float* ed   = (float*)carve((size_t)NN * 2 * 4);
  int2* rowinfo = (int2*)carve((size_t)NN * 8);
  int* csr    = (int*)carve((size_t)NBK * CAP * 4);
  uint32* packed = (uint32*)carve((size_t)NBK * CAP * 4);
  int* gcursor = (int*)carve(NBK * 4);

  hipMemsetAsync(gcursor, 0, NBK * 4, stream);

  // fused CSR partition + prep (independent block ranges)
  partition_prep_kernel<<<NTILES + NBX + 3, 256, 0, stream>>>(
      ei, gcursor, packed, x, W0, W1, lw, xb, w0t, w1t, lwt);
  build_kernel<<<NBK, 256, 0, stream>>>(packed, gcursor, rowinfo, csr);

  // layer 1
  gemm_att_kernel<<<(NN + 63) / 64, 256, 0, stream>>>(xb, w0t, as0, ad0, hfeat, es, ed, NN);
  aggregate_kernel<<<(NN * 64 + 255) / 256, 256, 0, stream>>>((const uint4*)hfeat, es, ed, rowinfo, csr, b0, h1b, NN);
  // layer 2
  gemm_att_kernel<<<(NN + 63) / 64, 256, 0, stream>>>(h1b, w1t, as1, ad1, hfeat, es, ed, NN);
  aggregate_kernel<<<(NN * 64 + 255) / 256, 256, 0, stream>>>((const uint4*)hfeat, es, ed, rowinfo, csr, b1, h2b, NN);
  // head
  final_kernel<<<(NN + 63) / 64, 256, 0, stream>>>(h1b, h2b, lwt, lb, out, NN);
}

// Round 16
// 246.445 us; speedup vs baseline: 1.0199x; 1.0199x over previous
//
#include <hip/hip_runtime.h>
#include <hip/hip_fp16.h>
#include <math.h>

#define NN 50000
#define E0 800000
#define ET 850000
#define NBX 200  // prep x-conversion blocks (+2 W transposes, +1 lw transpose)
#define NBK 196  // CSR buckets = ceil(NN/256), 256 nodes each
#define TILE 4096
#define NTILES 208  // ceil(ET/TILE)
#define CAP 8192    // per-bucket region (packed & padded csr)

typedef unsigned int uint32;
typedef unsigned short u16;
typedef __attribute__((ext_vector_type(8))) _Float16 f16x8;  // 8 f16 = 4 VGPRs
typedef __attribute__((ext_vector_type(4))) float f32x4;

__device__ __forceinline__ u16 f2h(float f) {
  return __half_as_ushort(__float2half(f));  // RNE
}
__device__ __forceinline__ float h2f(u16 u) {
  return __half2float(__ushort_as_half(u));
}

// ---- fused: CSR partition (blocks 0..NTILES-1) + prep (remaining blocks) ----
__global__ __launch_bounds__(256) void partition_prep_kernel(
    const int* __restrict__ ei, int* __restrict__ gcursor, uint32* __restrict__ packed,
    const float* __restrict__ x, const float* __restrict__ W0, const float* __restrict__ W1,
    const float* __restrict__ lw,
    u16* __restrict__ xb, u16* __restrict__ w0t, u16* __restrict__ w1t, u16* __restrict__ lwt)
{
  __shared__ __align__(16) char smem[23872];
  const int b = blockIdx.x;
  const int tid = threadIdx.x;
  if (b < NTILES) {
    int* hist = (int*)smem;                       // 784
    int* s    = (int*)(smem + 784);               // 1024
    int* scanb = (int*)(smem + 1808);             // 784
    int* gofs  = (int*)(smem + 2592);             // 784
    uint32* shuf = (uint32*)(smem + 3376);        // 16384
    unsigned char* sbkt = (unsigned char*)(smem + 19760);  // 4096
    const int t0 = b * TILE;
    for (int i = tid; i < NBK; i += 256) hist[i] = 0;
    __syncthreads();
    int myb[16]; int myr[16]; uint32 mypk[16];
#pragma unroll
    for (int i = 0; i < 16; ++i) {
      int e = t0 + i * 256 + tid;
      myb[i] = -1;
      if (e < ET) {
        int src, dst;
        if (e < E0) { src = ei[e]; dst = ei[E0 + e]; }
        else        { src = e - E0; dst = src; }
        myb[i] = dst >> 8;
        mypk[i] = ((uint32)(dst & 255) << 16) | (uint32)src;
        myr[i] = atomicAdd(&hist[myb[i]], 1);
      }
    }
    __syncthreads();
    int v = (tid < NBK) ? hist[tid] : 0;
    int val = v;
    s[tid] = val;
    __syncthreads();
#pragma unroll
    for (int off = 1; off < 256; off <<= 1) {
      int t = (tid >= off) ? s[tid - off] : 0;
      __syncthreads();
      val += t;
      s[tid] = val;
      __syncthreads();
    }
    if (tid < NBK) {
      scanb[tid] = val - v;
      gofs[tid] = (v > 0) ? atomicAdd(&gcursor[tid], v) : 0;
    }
    __syncthreads();
#pragma unroll
    for (int i = 0; i < 16; ++i) {
      if (myb[i] >= 0) {
        int slot = scanb[myb[i]] + myr[i];
        shuf[slot] = mypk[i];
        sbkt[slot] = (unsigned char)myb[i];
      }
    }
    __syncthreads();
    const int tcount = (t0 + TILE <= ET) ? TILE : (ET - t0);
    for (int i = tid; i < tcount; i += 256) {
      int bb = sbkt[i];
      packed[(size_t)bb * CAP + gofs[bb] + (i - scanb[bb])] = shuf[i];
    }
  } else {
    const int b2 = b - NTILES;
    if (b2 < NBX) {
      const float4* x4 = (const float4*)x;
      ushort4* xb4 = (ushort4*)xb;
      const int total = NN * 128 / 4;
      for (int i = b2 * 256 + tid; i < total; i += NBX * 256) {
        float4 v = x4[i];
        ushort4 u;
        u.x = f2h(v.x); u.y = f2h(v.y); u.z = f2h(v.z); u.w = f2h(v.w);
        xb4[i] = u;
      }
    } else if (b2 < NBX + 2) {
      const float* W = (b2 == NBX) ? W0 : W1;
      u16* Wt = (b2 == NBX) ? w0t : w1t;
      float (*tile)[129] = (float(*)[129])smem;   // 16.5 KB overlay
      for (int k0 = 0; k0 < 128; k0 += 32) {
        __syncthreads();
#pragma unroll
        for (int it = 0; it < 4; ++it) {
          int q = tid + it * 256;
          int kk = q >> 5, n4 = (q & 31) * 4;
          float4 v = *(const float4*)&W[(k0 + kk) * 128 + n4];
          tile[kk][n4 + 0] = v.x; tile[kk][n4 + 1] = v.y;
          tile[kk][n4 + 2] = v.z; tile[kk][n4 + 3] = v.w;
        }
        __syncthreads();
        int n = tid >> 1, h = (tid & 1) * 16;
        __align__(16) u16 tmp[16];
#pragma unroll
        for (int j = 0; j < 16; ++j) tmp[j] = f2h(tile[h + j][n]);
        *(uint4*)&Wt[n * 128 + k0 + h] = *(uint4*)&tmp[0];
        *(uint4*)&Wt[n * 128 + k0 + h + 8] = *(uint4*)&tmp[8];
      }
    } else {
      for (int idx = tid; idx < 48 * 256; idx += 256) {
        int j = idx >> 8, k = idx & 255;
        lwt[idx] = (j < 40) ? f2h(lw[k * 40 + j]) : (u16)0;
      }
    }
  }
}

// Pass 2: per bucket, padded local CSR in LDS (sentinel = NN), coalesced writes.
__global__ __launch_bounds__(256) void build_kernel(
    const uint32* __restrict__ packed, const int* __restrict__ gcursor,
    int2* __restrict__ rowinfo, int* __restrict__ csr_src)
{
  __shared__ int h[256];
  __shared__ int s[256];
  __shared__ int sc[256];
  __shared__ int cur[256];
  __shared__ int ptot_s;
  __shared__ u16 simg[CAP];
  const int b = blockIdx.x;
  const int tid = threadIdx.x;
  const int cnt = gcursor[b];
  const uint32* pk = packed + (size_t)b * CAP;
  h[tid] = 0;
  cur[tid] = 0;
  __syncthreads();
  for (int i = tid; i < cnt; i += 256) atomicAdd(&h[(pk[i] >> 16) & 255], 1);
  __syncthreads();
  const int pd = (h[tid] + 7) & ~7;   // pad to multiple of 8
  int val = pd;
  s[tid] = val;
  __syncthreads();
#pragma unroll
  for (int off = 1; off < 256; off <<= 1) {
    int t = (tid >= off) ? s[tid - off] : 0;
    __syncthreads();
    val += t;
    s[tid] = val;
    __syncthreads();
  }
  sc[tid] = val - pd;
  if (tid == 255) ptot_s = val;
  __syncthreads();
  const int ptot = ptot_s;
  for (int i = tid; i < ptot; i += 256) simg[i] = (u16)NN;   // sentinel fill
  __syncthreads();
  for (int i = tid; i < cnt; i += 256) {
    uint32 p = pk[i];
    int dl = (p >> 16) & 255;
    int r = atomicAdd(&cur[dl], 1);
    simg[sc[dl] + r] = (u16)(p & 0xFFFFu);
  }
  __syncthreads();
  int n = b * 256 + tid;
  if (n < NN) rowinfo[n] = make_int2(b * CAP + sc[tid], pd);
  for (int i = tid; i < ptot; i += 256) csr_src[b * CAP + i] = (int)simg[i];
}

// ---------------- MFMA GEMM (Xb @ W) + attention logits, f16 ----------------
__global__ __launch_bounds__(256) void gemm_att_kernel(
    const u16* __restrict__ Xb, const u16* __restrict__ Wt,
    const float* __restrict__ avs, const float* __restrict__ avd,
    u16* __restrict__ hfeat, float* __restrict__ es, float* __restrict__ ed,
    int nnodes)
{
  __shared__ u16 hout[64 * 136];   // 17.4 KB
  __shared__ float es_s[2][64];
  __shared__ float ed_s[2][64];
  const int tid = threadIdx.x;
  const int wid = tid >> 6, lane = tid & 63;
  const int quad = lane >> 4, lc = lane & 15;
  const int n0 = blockIdx.x * 64;
  if (blockIdx.x == 0 && tid < 2) es[2 * NN + tid] = -1e30f;  // sentinel logits -> w=0

  const int arow = wid * 16 + lc;
  const int rrow = min(n0 + arow, nnodes - 1);  // clamp tail (output guarded)

  f32x4 acc[8];
#pragma unroll
  for (int t = 0; t < 8; ++t) acc[t] = (f32x4){0.f, 0.f, 0.f, 0.f};
#pragma unroll
  for (int ks = 0; ks < 4; ++ks) {
    const int k0 = ks * 32 + quad * 8;
    f16x8 a = *(const f16x8*)&Xb[(size_t)rrow * 128 + k0];
#pragma unroll
    for (int t = 0; t < 8; ++t) {
      f16x8 b = *(const f16x8*)&Wt[(t * 16 + lc) * 128 + k0];  // L2-resident
      acc[t] = __builtin_amdgcn_mfma_f32_16x16x32_f16(a, b, acc[t], 0, 0, 0);
    }
  }

  // attention partials: quad-local shuffle reduction (single writer, no atomics)
  float av_s[8], av_d[8];
#pragma unroll
  for (int t = 0; t < 8; ++t) { av_s[t] = avs[t * 16 + lc]; av_d[t] = avd[t * 16 + lc]; }
#pragma unroll
  for (int r = 0; r < 4; ++r) {
    float s0 = 0.f, s1 = 0.f, d0 = 0.f, d1 = 0.f;
#pragma unroll
    for (int t = 0; t < 4; ++t) { s0 += acc[t][r] * av_s[t]; d0 += acc[t][r] * av_d[t]; }
#pragma unroll
    for (int t = 4; t < 8; ++t) { s1 += acc[t][r] * av_s[t]; d1 += acc[t][r] * av_d[t]; }
#pragma unroll
    for (int m = 1; m < 16; m <<= 1) {
      s0 += __shfl_xor(s0, m); s1 += __shfl_xor(s1, m);
      d0 += __shfl_xor(d0, m); d1 += __shfl_xor(d1, m);
    }
    if (lc == 0) {
      int row = wid * 16 + quad * 4 + r;
      es_s[0][row] = s0; es_s[1][row] = s1;
      ed_s[0][row] = d0; ed_s[1][row] = d1;
    }
  }
  // f16 output roundtrip for coalesced writeback
#pragma unroll
  for (int t = 0; t < 8; ++t)
#pragma unroll
    for (int r = 0; r < 4; ++r)
      hout[(wid * 16 + quad * 4 + r) * 136 + t * 16 + lc] = f2h(acc[t][r]);
  __syncthreads();
#pragma unroll
  for (int it = 0; it < 4; ++it) {
    int g = tid + it * 256;
    int r = g >> 4, c8 = (g & 15) * 8;
    if (n0 + r < nnodes)
      *(uint4*)&hfeat[(size_t)(n0 + r) * 128 + c8] = *(const uint4*)&hout[r * 136 + c8];
  }
  if (tid < 64) {
    int n = n0 + tid;
    if (n < nnodes) {
      es[n * 2 + 0] = es_s[0][tid]; es[n * 2 + 1] = es_s[1][tid];
      ed[n * 2 + 0] = ed_s[0][tid]; ed[n * 2 + 1] = ed_s[1][tid];
    }
  }
}

// ---------------- aggregation: one wave per node, 8 edges/iter, f16 mix-FMA ----------------
__global__ __launch_bounds__(256) void aggregate_kernel(
    const uint4* __restrict__ hfeat4, const float* __restrict__ es, const float* __restrict__ ed,
    const int2* __restrict__ rowinfo, const int* __restrict__ csr_src,
    const float* __restrict__ bias, u16* __restrict__ out, int nnodes)
{
  int n = (blockIdx.x * blockDim.x + threadIdx.x) >> 6;
  int lane = threadIdx.x & 63;
  if (n >= nnodes) return;
  const int eg = lane >> 4;
  const int fl = lane & 15;
  const int hd = (fl >= 8) ? 1 : 0;
  const int2 ri = rowinfo[n];
  const int nch = ri.y >> 3;
  const int j0 = ri.x + eg;
  const float edn = ed[n * 2 + hd];

  float acc[8];
#pragma unroll
  for (int t = 0; t < 8; ++t) acc[t] = 0.f;
  float den = 0.f;

  int i0A = csr_src[j0], i1A = csr_src[j0 + 4];
  float e0 = es[i0A * 2 + hd] + edn; e0 = fmaxf(e0, 0.2f * e0);
  float e1 = es[i1A * 2 + hd] + edn; e1 = fmaxf(e1, 0.2f * e1);
  float w0A = __expf(e0), w1A = __expf(e1);
  for (int c = 0;;) {
    uint4 h0 = hfeat4[(size_t)i0A * 16 + fl];
    uint4 h1 = hfeat4[(size_t)i1A * 16 + fl];
    bool more = (c + 1 < nch);
    int i0B, i1B; float w0B, w1B;
    if (more) {
      int jb = j0 + (c + 1) * 8;
      i0B = csr_src[jb]; i1B = csr_src[jb + 4];
      float f0 = es[i0B * 2 + hd] + edn; f0 = fmaxf(f0, 0.2f * f0);
      float f1 = es[i1B * 2 + hd] + edn; f1 = fmaxf(f1, 0.2f * f1);
      w0B = __expf(f0); w1B = __expf(f1);
    }
    // f16 unpack folds into v_fma_mix_f32 (fp32 acc, f16 src via op_sel)
    acc[0] = fmaf(w0A, h2f((u16)(h0.x & 0xFFFFu)), acc[0]);
    acc[1] = fmaf(w0A, h2f((u16)(h0.x >> 16)),     acc[1]);
    acc[2] = fmaf(w0A, h2f((u16)(h0.y & 0xFFFFu)), acc[2]);
    acc[3] = fmaf(w0A, h2f((u16)(h0.y >> 16)),     acc[3]);
    acc[4] = fmaf(w0A, h2f((u16)(h0.z & 0xFFFFu)), acc[4]);
    acc[5] = fmaf(w0A, h2f((u16)(h0.z >> 16)),     acc[5]);
    acc[6] = fmaf(w0A, h2f((u16)(h0.w & 0xFFFFu)), acc[6]);
    acc[7] = fmaf(w0A, h2f((u16)(h0.w >> 16)),     acc[7]);
    acc[0] = fmaf(w1A, h2f((u16)(h1.x & 0xFFFFu)), acc[0]);
    acc[1] = fmaf(w1A, h2f((u16)(h1.x >> 16)),     acc[1]);
    acc[2] = fmaf(w1A, h2f((u16)(h1.y & 0xFFFFu)), acc[2]);
    acc[3] = fmaf(w1A, h2f((u16)(h1.y >> 16)),     acc[3]);
    acc[4] = fmaf(w1A, h2f((u16)(h1.z & 0xFFFFu)), acc[4]);
    acc[5] = fmaf(w1A, h2f((u16)(h1.z >> 16)),     acc[5]);
    acc[6] = fmaf(w1A, h2f((u16)(h1.w & 0xFFFFu)), acc[6]);
    acc[7] = fmaf(w1A, h2f((u16)(h1.w >> 16)),     acc[7]);
    den += w0A + w1A;
    if (!more) break;
    i0A = i0B; i1A = i1B; w0A = w0B; w1A = w1B;
    ++c;
  }

#pragma unroll
  for (int t = 0; t < 8; ++t) {
    acc[t] += __shfl_xor(acc[t], 16);
    acc[t] += __shfl_xor(acc[t], 32);
  }
  den += __shfl_xor(den, 16);
  den += __shfl_xor(den, 32);

  if (eg == 0) {
    float inv = 1.f / den;
    float4 b0 = *(const float4*)&bias[fl * 8];
    float4 b1 = *(const float4*)&bias[fl * 8 + 4];
    float bv[8] = {b0.x, b0.y, b0.z, b0.w, b1.x, b1.y, b1.z, b1.w};
    u16 pk[8];
#pragma unroll
    for (int t = 0; t < 8; ++t) {
      float v = acc[t] * inv + bv[t];
      v = (v > 0.f) ? v : (__expf(v) - 1.f);  // ELU
      pk[t] = f2h(v);
    }
    uint4 o;
    o.x = (uint32)pk[0] | ((uint32)pk[1] << 16);
    o.y = (uint32)pk[2] | ((uint32)pk[3] << 16);
    o.z = (uint32)pk[4] | ((uint32)pk[5] << 16);
    o.w = (uint32)pk[6] | ((uint32)pk[7] << 16);
    ((uint4*)out)[(size_t)n * 16 + fl] = o;
  }
}

// ---------------- final: MFMA [64x256] @ [256x48] + log_softmax, zero LDS ----------------
__global__ __launch_bounds__(256) void final_kernel(
    const u16* __restrict__ h1b, const u16* __restrict__ h2b,
    const u16* __restrict__ lwt, const float* __restrict__ lb,
    float* __restrict__ out, int nnodes)
{
  const int tid = threadIdx.x;
  const int wid = tid >> 6, lane = tid & 63;
  const int quad = lane >> 4, lc = lane & 15;
  const int n0 = blockIdx.x * 64;
  const int arow = wid * 16 + lc;
  const int rrow = min(n0 + arow, nnodes - 1);

  f32x4 acc[3];
#pragma unroll
  for (int t = 0; t < 3; ++t) acc[t] = (f32x4){0.f, 0.f, 0.f, 0.f};
#pragma unroll
  for (int ks = 0; ks < 8; ++ks) {
    const u16* hsrc = (ks < 4) ? h1b : h2b;
    const int k0 = (ks & 3) * 32 + quad * 8;
    const int kl = ks * 32 + quad * 8;
    f16x8 a = *(const f16x8*)&hsrc[(size_t)rrow * 128 + k0];
#pragma unroll
    for (int t = 0; t < 3; ++t) {
      f16x8 b = *(const f16x8*)&lwt[(t * 16 + lc) * 256 + kl];  // L2-resident
      acc[t] = __builtin_amdgcn_mfma_f32_16x16x32_f16(a, b, acc[t], 0, 0, 0);
    }
  }

  float bv[3];
  bool valid[3];
#pragma unroll
  for (int t = 0; t < 3; ++t) {
    int col = t * 16 + lc;
    valid[t] = (col < 40);
    bv[t] = valid[t] ? lb[col] : 0.f;
  }
#pragma unroll
  for (int r = 0; r < 4; ++r) {
    int row = wid * 16 + quad * 4 + r;
    int n = n0 + row;
    float v[3];
    float mx = -INFINITY;
#pragma unroll
    for (int t = 0; t < 3; ++t) {
      v[t] = acc[t][r] + bv[t];
      if (valid[t]) mx = fmaxf(mx, v[t]);
    }
    mx = fmaxf(mx, __shfl_xor(mx, 1));
    mx = fmaxf(mx, __shfl_xor(mx, 2));
    mx = fmaxf(mx, __shfl_xor(mx, 4));
    mx = fmaxf(mx, __shfl_xor(mx, 8));
    float s = 0.f;
#pragma unroll
    for (int t = 0; t < 3; ++t) if (valid[t]) s += __expf(v[t] - mx);
    s += __shfl_xor(s, 1);
    s += __shfl_xor(s, 2);
    s += __shfl_xor(s, 4);
    s += __shfl_xor(s, 8);
    float lg = mx + __logf(s);
    if (n < nnodes) {
#pragma unroll
      for (int t = 0; t < 3; ++t)
        if (valid[t]) out[(size_t)n * 40 + t * 16 + lc] = v[t] - lg;
    }
  }
}

// ---------------- launch ----------------

extern "C" void kernel_launch(void* const* d_in, const int* in_sizes, int n_in,
                              void* d_out, int out_size, void* d_ws, size_t ws_size,
                              hipStream_t stream) {
  const float* x   = (const float*)d_in[0];
  const int*   ei  = (const int*)d_in[1];
  const float* W0  = (const float*)d_in[2];
  const float* as0 = (const float*)d_in[3];
  const float* ad0 = (const float*)d_in[4];
  const float* b0  = (const float*)d_in[5];
  const float* W1  = (const float*)d_in[6];
  const float* as1 = (const float*)d_in[7];
  const float* ad1 = (const float*)d_in[8];
  const float* b1  = (const float*)d_in[9];
  const float* lw  = (const float*)d_in[10];
  const float* lb  = (const float*)d_in[11];
  float* out = (float*)d_out;

  char* p = (char*)d_ws;
  auto carve = [&](size_t bytes) { char* r = p; p += (bytes + 255) & ~(size_t)255; return r; };
  u16* xb     = (u16*)carve((size_t)NN * 128 * 2);
  u16* w0t    = (u16*)carve(128 * 128 * 2);
  u16* w1t    = (u16*)carve(128 * 128 * 2);
  u16* lwt    = (u16*)carve(48 * 256 * 2);
  u16* hfeat  = (u16*)carve((size_t)(NN + 1) * 128 * 2);  // +1 sentinel row
  u16* h1b    = (u16*)carve((size_t)NN * 128 * 2);
  u16* h2b    = (u16*)carve((size_t)NN * 128 * 2);
  float* es   = (float*)carve((size_t)(NN + 1) * 2 * 4);  // +sentinel logits
  float* ed   = (float*)carve((size_t)NN * 2 * 4);
  int2* rowinfo = (int2*)carve((size_t)NN * 8);
  int* csr    = (int*)carve((size_t)NBK * CAP * 4);
  uint32* packed = (uint32*)carve((size_t)NBK * CAP * 4);
  int* gcursor = (int*)carve(NBK * 4);

  hipMemsetAsync(gcursor, 0, NBK * 4, stream);

  // fused CSR partition + prep (independent block ranges)
  partition_prep_kernel<<<NTILES + NBX + 3, 256, 0, stream>>>(
      ei, gcursor, packed, x, W0, W1, lw, xb, w0t, w1t, lwt);
  build_kernel<<<NBK, 256, 0, stream>>>(packed, gcursor, rowinfo, csr);

  // layer 1
  gemm_att_kernel<<<(NN + 63) / 64, 256, 0, stream>>>(xb, w0t, as0, ad0, hfeat, es, ed, NN);
  aggregate_kernel<<<(NN * 64 + 255) / 256, 256, 0, stream>>>((const uint4*)hfeat, es, ed, rowinfo, csr, b0, h1b, NN);
  // layer 2
  gemm_att_kernel<<<(NN + 63) / 64, 256, 0, stream>>>(h1b, w1t, as1, ad1, hfeat, es, ed, NN);
  aggregate_kernel<<<(NN * 64 + 255) / 256, 256, 0, stream>>>((const uint4*)hfeat, es, ed, rowinfo, csr, b1, h2b, NN);
  // head
  final_kernel<<<(NN + 63) / 64, 256, 0, stream>>>(h1b, h2b, lwt, lb, out, NN);
}